// Round 10
// baseline (307.758 us; speedup 1.0000x reference)
//
#include <hip/hip_runtime.h>
#include <hip/hip_fp16.h>
#include <math.h>

#define GHH 224
#define GWW 224
#define HW (GHH*GWW)     // 50176
#define BATCH 8
#define RAD 3
#define DIAM 7
#define QC 32
#define TILE 16
#define TP (TILE + 2*RAD)   // 22
#define TPIX (TP*TP)        // 484
#define CS 485              // chunk-plane stride in float4 (proven layout)

// LDS layout: [hrh: 8 planes x 22 rows x 24 cols f16 = 8448 B][sq: 4*485*16 = 31040 B]
// hrh planes 0-3 = hi{x,y,z,1}, 4-7 = lo{x,y,z,0}. Total 39488 B -> 4 blocks/CU.
#define HRH_COLS 24
#define PSTR (TP*HRH_COLS)   // 528 halves per plane
#define HRH_B (8*PSTR*2)     // 8448 B
#define SMEM_B (HRH_B + 4*CS*16)  // 39488

#define L2E 1.44269504f

typedef _Float16 h2 __attribute__((ext_vector_type(2)));
typedef _Float16 v8h __attribute__((ext_vector_type(8)));
typedef float v4f __attribute__((ext_vector_type(4)));

__device__ __forceinline__ int refl(int i) {
    if (i < 0) i = -i;
    if (i >= GHH) i = 2 * GHH - 2 - i;
    return i;
}

__device__ __forceinline__ float gelu_fast(float v) {
    float u = 0.7978845608f * v * (1.f + 0.044715f * v * v);
    float e = __builtin_amdgcn_exp2f(u * (2.f * L2E));   // exp(2u), folded log2e
    float th = 1.f - 2.f / (e + 1.f);
    return 0.5f * v * (1.f + th);
}

// ---------------- linear + w2 B-frag prep + w1 f16 pack + guid4 pack ----------------
__global__ void linear_prep_kernel(const float* __restrict__ x,
                                   const float* __restrict__ W,
                                   const float* __restrict__ bias,
                                   float* __restrict__ f0,
                                   const float* __restrict__ w2s,
                                   __half* __restrict__ wsB,
                                   const float* __restrict__ w1s,
                                   const float* __restrict__ b1s,
                                   __half* __restrict__ wsW1,
                                   const float* __restrict__ guid,
                                   float4* __restrict__ guid4) {
    int blk = blockIdx.x;
    if (blk >= 1946) {   // guid4 pack: 1568 blocks
        int i = (blk - 1946) * 256 + threadIdx.x;
        int b = i / HW, pix = i % HW;
        guid4[i] = make_float4(guid[(b * 3) * HW + pix],
                               guid[(b * 3 + 1) * HW + pix],
                               guid[(b * 3 + 2) * HW + pix], 0.f);
        return;
    }
    if (blk == 1945) {   // pack w1/b1 (4 stages x 32 ch) into f16 quads (w0,w1,w2,b)
        int tid = threadIdx.x;
        if (tid < 128) {
            int s = tid >> 5, c = tid & 31;
            wsW1[tid * 4 + 0] = __float2half(w1s[s * 96 + c * 3 + 0]);
            wsW1[tid * 4 + 1] = __float2half(w1s[s * 96 + c * 3 + 1]);
            wsW1[tid * 4 + 2] = __float2half(w1s[s * 96 + c * 3 + 2]);
            wsW1[tid * 4 + 3] = __float2half(b1s[s * 32 + c]);
        }
        return;
    }
    if (blk == 1944) {   // pack w2 (4 stages) into f16 MFMA fragments
        int tid = threadIdx.x;
        int s = tid >> 6, l = tid & 63;
        int n0 = l & 15, kq = l >> 4;
        const float* w2 = w2s + s * 1024;
        __half* dst = wsB + (size_t)tid * 16;
        #pragma unroll
        for (int j = 0; j < 8; j++) {
            dst[j]     = __float2half(w2[n0 * QC + kq * 8 + j]);
            dst[8 + j] = __float2half(w2[(n0 + 16) * QC + kq * 8 + j]);
        }
        return;
    }
    int gwave = (blk * blockDim.x + threadIdx.x) >> 6;
    int lane = threadIdx.x & 63;
    if (gwave >= BATCH * 972) return;
    int b = gwave / 972, j = gwave % 972;
    const float* xr = x + b * 1000;
    const float* wr = W + j * 1000;
    float s = 0.f;
    for (int k = lane; k < 1000; k += 64)
        s += xr[k] * wr[k];
    #pragma unroll
    for (int off = 32; off; off >>= 1) s += __shfl_down(s, off, 64);
    if (lane == 0) f0[gwave] = s + bias[j];
}

// ---------------- bicubic 18 -> 224, float4-interleaved output ----------------
__device__ __forceinline__ float cubicw(float d) {
    d = fabsf(d);
    if (d <= 1.f) return ((1.25f * d - 2.25f) * d) * d + 1.f;
    if (d < 2.f)  return ((-0.75f * d + 3.75f) * d - 6.f) * d + 3.f;
    return 0.f;
}

__global__ void bicubic_kernel(const float* __restrict__ f0, float4* __restrict__ hr4) {
    int idx = blockIdx.x * blockDim.x + threadIdx.x;
    if (idx >= BATCH * HW) return;
    int pix = idx % HW;
    int b = idx / HW;
    int w = pix % GWW, h = pix / GWW;
    float xx = (w + 0.5f) * (18.f / 224.f) - 0.5f;
    float yy = (h + 0.5f) * (18.f / 224.f) - 0.5f;
    float fx0 = floorf(xx), fy0 = floorf(yy);
    int x0 = (int)fx0, y0 = (int)fy0;
    float tx = xx - fx0, ty = yy - fy0;
    float wx[4], wy[4];
    int ix[4], iy[4];
    #pragma unroll
    for (int k = 0; k < 4; k++) {
        wx[k] = cubicw(tx - (float)(k - 1));
        wy[k] = cubicw(ty - (float)(k - 1));
        int a = x0 + (k - 1); ix[k] = min(max(a, 0), 17);
        a = y0 + (k - 1);     iy[k] = min(max(a, 0), 17);
    }
    float acc[3];
    #pragma unroll
    for (int c = 0; c < 3; c++) {
        const float* src = f0 + (b * 3 + c) * 324;
        float a = 0.f;
        #pragma unroll
        for (int ky = 0; ky < 4; ky++) {
            float rowv = 0.f;
            #pragma unroll
            for (int kx = 0; kx < 4; kx++) rowv += wx[kx] * src[iy[ky] * 18 + ix[kx]];
            a += wy[ky] * rowv;
        }
        acc[c] = a;
    }
    hr4[idx] = make_float4(acc[0], acc[1], acc[2], 0.f);
}

// ---------------- q precompute: per-stage whole-image range_proj (R8-validated) ----------------
// Per-stage launch right before its jbu: producer->consumer through the SAME 25.7 MB
// buffer keeps it L3-resident (R9 lesson: batching all 4 stages forces a 103 MB HBM
// round-trip, 50.8 us). Layout: qimg[(b*4 + P)*HW + pix].
__global__ __launch_bounds__(256) void q_kernel(
    const float4* __restrict__ guid4,
    const __half* __restrict__ wsW1,
    const __half* __restrict__ wsB, const float* __restrict__ b2,
    float4* __restrict__ qimg,
    int stage)
{
    const int tid = threadIdx.x;
    const int l = tid & 63;
    const int gw = (blockIdx.x * 256 + tid) >> 6;    // 0..3135 (784 blocks x 4 waves)
    const int n0 = l & 15, kq = l >> 4;
    const int b = gw / 392;                          // 392 waves per batch image
    const int pix0 = (gw - b * 392) * 128;

    const v8h* Bp = (const v8h*)(wsB + ((size_t)stage * 64 + l) * 16);
    const v8h W2a = Bp[0], W2b = Bp[1];
    const float4 b2a = *(const float4*)(b2 + 4 * kq);
    const float4 b2b = *(const float4*)(b2 + 16 + 4 * kq);
    union { _Float16 h[32]; float4 f4[4]; } W1;
    {
        const float4* wp = (const float4*)(wsW1 + stage * 128 + kq * 32);
        W1.f4[0] = wp[0]; W1.f4[1] = wp[1]; W1.f4[2] = wp[2]; W1.f4[3] = wp[3];
    }
    const int plane0 = kq >> 1;
    const int boff   = (kq & 1) * 8;
    char* qc = (char*)qimg;

    #pragma unroll 1
    for (int it = 0; it < 8; it++) {
        int pix = pix0 + it * 16 + n0;
        float4 g = guid4[(size_t)b * HW + pix];
        union { _Float16 h[8]; v8h v; } A;
        #pragma unroll
        for (int j = 0; j < 8; j++) {
            float vv = fmaf((float)W1.h[j * 4], g.x,
                       fmaf((float)W1.h[j * 4 + 1], g.y,
                       fmaf((float)W1.h[j * 4 + 2], g.z, (float)W1.h[j * 4 + 3])));
            A.h[j] = (_Float16)gelu_fast(vv);
        }
        v4f D0 = {0.f, 0.f, 0.f, 0.f}, D1 = {0.f, 0.f, 0.f, 0.f};
        D0 = __builtin_amdgcn_mfma_f32_16x16x32_f16(W2a, A.v, D0, 0, 0, 0);
        D1 = __builtin_amdgcn_mfma_f32_16x16x32_f16(W2b, A.v, D1, 0, 0, 0);
        union { _Float16 h[4]; uint2 u; } q0, q1;
        q0.h[0] = (_Float16)(D0[0] + b2a.x);
        q0.h[1] = (_Float16)(D0[1] + b2a.y);
        q0.h[2] = (_Float16)(D0[2] + b2a.z);
        q0.h[3] = (_Float16)(D0[3] + b2a.w);
        q1.h[0] = (_Float16)(D1[0] + b2b.x);
        q1.h[1] = (_Float16)(D1[1] + b2b.y);
        q1.h[2] = (_Float16)(D1[2] + b2b.z);
        q1.h[3] = (_Float16)(D1[3] + b2b.w);
        *(uint2*)(qc + ((size_t)(b * 4 + plane0) * HW + pix) * 16 + boff)     = q0.u;
        *(uint2*)(qc + ((size_t)(b * 4 + 2 + plane0) * HW + pix) * 16 + boff) = q1.u;
    }
}

// ---------------- fused JBU: stage q window -> MFMA scores -> exp2 -> MFMA conv ----------------
// Streaming with #pragma unroll 2 (R9: no spill after phase-0 hoist; ~5 us/dispatch).
__global__ __launch_bounds__(256, 4) void jbu_kernel(
    const float4* __restrict__ qimg,
    const float4* __restrict__ hr4,
    float4* __restrict__ out4,
    float* __restrict__ outP,
    const float* __restrict__ temps,
    const float* __restrict__ sigmas,
    int stage)
{
    __shared__ __align__(16) char smem[SMEM_B];
    _Float16* hrh = (_Float16*)smem;            // [8][22][24] f16
    char* sqb = smem + HRH_B;                   // q tile f16 chunk-planar [4][CS] float4
    float4* sqf4 = (float4*)sqb;

    const int tx = threadIdx.x, ty = threadIdx.y;
    const int tid = ty * TILE + tx;
    const int b = blockIdx.z;
    const int h0 = blockIdx.y * TILE, w0 = blockIdx.x * TILE;

    // ---- stage q window (4 planes) + hr tile (f16 hi/lo) from global ----
    const float4* qb = qimg + (size_t)b * 4 * HW;
    const float4* hb = hr4 + (size_t)b * HW;
    for (int i = tid; i < TPIX; i += 256) {
        int r = i / TP, cx = i % TP;
        int gh = refl(h0 - RAD + r), gw = refl(w0 - RAD + cx);
        size_t gpix = (size_t)gh * GWW + gw;
        sqf4[i]          = qb[gpix];
        sqf4[CS + i]     = qb[HW + gpix];
        sqf4[2 * CS + i] = qb[2 * HW + gpix];
        sqf4[3 * CS + i] = qb[3 * HW + gpix];
        float4 v = hb[gpix];
        _Float16 hx = (_Float16)v.x, hy = (_Float16)v.y, hz = (_Float16)v.z;
        int base = r * HRH_COLS + cx;
        hrh[0 * PSTR + base] = hx;
        hrh[1 * PSTR + base] = hy;
        hrh[2 * PSTR + base] = hz;
        hrh[3 * PSTR + base] = (_Float16)1.0f;
        hrh[4 * PSTR + base] = (_Float16)(v.x - (float)hx);
        hrh[5 * PSTR + base] = (_Float16)(v.y - (float)hy);
        hrh[6 * PSTR + base] = (_Float16)(v.z - (float)hz);
        hrh[7 * PSTR + base] = (_Float16)0.0f;
    }
    // zero pad cols 22,23 (read by masked-0 weights; must be finite, not LDS residue)
    for (int i = tid; i < 8 * TP * 2; i += 256) {
        int p = i / (TP * 2), rem = i % (TP * 2);
        int r = rem >> 1, cc = 22 + (rem & 1);
        hrh[p * PSTR + r * HRH_COLS + cc] = (_Float16)0.0f;
    }
    __syncthreads();   // hrh + sq ready

    // ---- streaming: MFMA scores -> exp2 weights -> MFMA conv ----
    const int wv = tid >> 6;
    const int l = tid & 63;
    const int g = l >> 4, c = l & 15;      // g = k-chunk group, c = center col

    float t = __expf(temps[stage]);
    t = fminf(fmaxf(t, 1e-4f), 1e4f);
    const float tl2 = t * L2E;             // folded: exp(t*s+lc) = exp2(s*tl2 + lc2)
    float sig = sigmas[stage];
    float inv2s2 = 1.f / (2.f * sig * sig);
    float sdv[DIAM];
    #pragma unroll
    for (int i = 0; i < DIAM; i++) {
        float d = (float)(i - 3) * (1.f / 3.f);
        sdv[i] = __expf(-d * d * inv2s2);
    }
    // lc2[jj]: log2-domain spatial-x for tap k = 8g+jj at center c; -1.44e38 masks
    float lc2[8];
    #pragma unroll
    for (int jj = 0; jj < 8; jj++) {
        int dj = 8 * g + jj - c;
        float d = (float)(dj - 3) * (1.f / 3.f);
        lc2[jj] = (dj >= 0 && dj <= 6) ? (-d * d * inv2s2 * L2E) : -1.44e38f;
    }
    // neighbor-col loads (per lane, m = c): sigma_cb(c) clamped to row end
    const int nbb = 8 * (c >> 2) + (c & 3);
    const int nb0 = min(nbb, 21);
    const int nb1 = min(nbb + 4, 21);
    const int pA = c & 3;                  // hr channel plane for conv A-frag

    #pragma unroll 2
    for (int rr = 0; rr < 4; rr++) {
        const int row = wv * 4 + rr;
        // center B-frag (reused across di/cb): q[center row][col c][chunk g]
        const v8h Bc = *(const v8h*)(sqb + (size_t)(g * CS + (row + RAD) * TP + RAD + c) * 16);
        v4f D2 = {0.f, 0.f, 0.f, 0.f};
        #pragma unroll
        for (int di = 0; di < DIAM; di++) {
            const int prow = row + di;
            const v8h A0 = *(const v8h*)(sqb + (size_t)(g * CS + prow * TP + nb0) * 16);
            const v8h A1 = *(const v8h*)(sqb + (size_t)(g * CS + prow * TP + nb1) * 16);
            v4f S0 = {0.f, 0.f, 0.f, 0.f}, S1 = {0.f, 0.f, 0.f, 0.f};
            S0 = __builtin_amdgcn_mfma_f32_16x16x32_f16(A0, Bc, S0, 0, 0, 0);
            S1 = __builtin_amdgcn_mfma_f32_16x16x32_f16(A1, Bc, S1, 0, 0, 0);
            const float sy = sdv[di];
            union { _Float16 h[8]; v8h v; } Wg;
            #pragma unroll
            for (int j = 0; j < 4; j++) {
                Wg.h[j]     = (_Float16)(__builtin_amdgcn_exp2f(fmaf(S0[j], tl2, lc2[j])) * sy);
                Wg.h[4 + j] = (_Float16)(__builtin_amdgcn_exp2f(fmaf(S1[j], tl2, lc2[4 + j])) * sy);
            }
            const v8h Hh = *(const v8h*)(smem + (size_t)((pA * TP + prow) * HRH_COLS + 8 * g) * 2);
            const v8h Hl = *(const v8h*)(smem + (size_t)(((pA + 4) * TP + prow) * HRH_COLS + 8 * g) * 2);
            D2 = __builtin_amdgcn_mfma_f32_16x16x32_f16(Hh, Wg.v, D2, 0, 0, 0);
            D2 = __builtin_amdgcn_mfma_f32_16x16x32_f16(Hl, Wg.v, D2, 0, 0, 0);
        }
        if (l < 16) {   // lanes 0..15 hold D2 rows 0..3 = {x,y,z,wsum} for center c
            float rk = 1.f / fmaxf(D2[3], 1e-7f);   // reference floor: clip(wsum, 1e-7)
            if (stage < 3) {
                out4[(size_t)b * HW + (size_t)(h0 + row) * GWW + (w0 + c)] =
                    make_float4(D2[0] * rk, D2[1] * rk, D2[2] * rk, 0.f);
            } else {
                size_t obase = (size_t)b * 3 * HW + (size_t)(h0 + row) * GWW + (w0 + c);
                outP[obase]          = D2[0] * rk;
                outP[obase + HW]     = D2[1] * rk;
                outP[obase + 2 * HW] = D2[2] * rk;
            }
        }
    }
}

extern "C" void kernel_launch(void* const* d_in, const int* in_sizes, int n_in,
                              void* d_out, int out_size, void* d_ws, size_t ws_size,
                              hipStream_t stream) {
    const float* x      = (const float*)d_in[0];
    const float* guid   = (const float*)d_in[1];
    const float* lw     = (const float*)d_in[2];
    const float* lb     = (const float*)d_in[3];
    const float* w1s    = (const float*)d_in[4];
    const float* b1s    = (const float*)d_in[5];
    const float* w2s    = (const float*)d_in[6];
    const float* b2s    = (const float*)d_in[7];
    const float* temps  = (const float*)d_in[8];
    const float* sigmas = (const float*)d_in[9];

    char* ws = (char*)d_ws;
    const size_t P4_BYTES = (size_t)BATCH * HW * sizeof(float4);      // 6,422,528
    float4* guid4 = (float4*)ws;
    float4* hr4A  = (float4*)(ws + P4_BYTES);
    float4* hr4B  = (float4*)(ws + 2 * P4_BYTES);
    float*  f0    = (float*)(ws + 3 * P4_BYTES);                      // 31,104 B
    __half* wsB   = (__half*)(ws + 3 * P4_BYTES + 31104);             //  8,192 B
    __half* wsW1  = (__half*)(ws + 3 * P4_BYTES + 31104 + 8192);      //  1,024 B
    float4* qimg  = (float4*)(ws + 3 * P4_BYTES + 40320);             // 25,690,112 B (per-stage reuse)

    linear_prep_kernel<<<1946 + 1568, 256, 0, stream>>>(
        x, lw, lb, f0, w2s, wsB, w1s, b1s, wsW1, guid, guid4);
    bicubic_kernel<<<(BATCH * HW + 255) / 256, 256, 0, stream>>>(f0, hr4A);

    dim3 jgrid(14, 14, BATCH), jblock(16, 16);
    const float4* hins[4]  = { hr4A, hr4B, hr4A, hr4B };
    float4*       fouts[4] = { hr4B, hr4A, hr4B, nullptr };
    for (int s = 0; s < 4; s++) {
        q_kernel<<<784, 256, 0, stream>>>(guid4, wsW1, wsB, b2s + s * 32, qimg, s);
        jbu_kernel<<<jgrid, jblock, 0, stream>>>(
            qimg, hins[s], fouts[s], (s == 3) ? (float*)d_out : nullptr,
            temps, sigmas, s);
    }
}

// Round 11
// 284.243 us; speedup vs baseline: 1.0827x; 1.0827x over previous
//
#include <hip/hip_runtime.h>
#include <hip/hip_fp16.h>
#include <math.h>

#define GHH 224
#define GWW 224
#define HW (GHH*GWW)     // 50176
#define BATCH 8
#define RAD 3
#define DIAM 7
#define QC 32
#define TILE 16
#define TP (TILE + 2*RAD)   // 22
#define TPIX (TP*TP)        // 484
#define CS 485              // chunk-plane stride in float4 (proven layout)

// LDS layout: [hrh: 8 planes x 22 rows x 24 cols f16 = 8448 B][sq: 4*485*16 = 31040 B]
// hrh planes 0-3 = hi{x,y,z,1}, 4-7 = lo{x,y,z,0}. Total 39488 B -> 4 blocks/CU.
#define HRH_COLS 24
#define PSTR (TP*HRH_COLS)   // 528 halves per plane
#define HRH_B (8*PSTR*2)     // 8448 B
#define SMEM_B (HRH_B + 4*CS*16)  // 39488

#define L2E 1.44269504f

typedef _Float16 h2 __attribute__((ext_vector_type(2)));
typedef _Float16 v8h __attribute__((ext_vector_type(8)));
typedef float v4f __attribute__((ext_vector_type(4)));

__device__ __forceinline__ int refl(int i) {
    if (i < 0) i = -i;
    if (i >= GHH) i = 2 * GHH - 2 - i;
    return i;
}

__device__ __forceinline__ float gelu_fast(float v) {
    float u = 0.7978845608f * v * (1.f + 0.044715f * v * v);
    float e = __builtin_amdgcn_exp2f(u * (2.f * L2E));   // exp(2u), folded log2e
    float th = 1.f - 2.f / (e + 1.f);
    return 0.5f * v * (1.f + th);
}

__device__ __forceinline__ float cubicw(float d) {
    d = fabsf(d);
    if (d <= 1.f) return ((1.25f * d - 2.25f) * d) * d + 1.f;
    if (d < 2.f)  return ((-0.75f * d + 3.75f) * d - 6.f) * d + 3.f;
    return 0.f;
}

// Exact replica of the validated bicubic_kernel math for one output pixel.
__device__ __forceinline__ float4 bicubic_px(const float* __restrict__ f0, int b, int h, int w) {
    float xx = (w + 0.5f) * (18.f / 224.f) - 0.5f;
    float yy = (h + 0.5f) * (18.f / 224.f) - 0.5f;
    float fx0 = floorf(xx), fy0 = floorf(yy);
    int x0 = (int)fx0, y0 = (int)fy0;
    float tx = xx - fx0, ty = yy - fy0;
    float wx[4], wy[4];
    int ix[4], iy[4];
    #pragma unroll
    for (int k = 0; k < 4; k++) {
        wx[k] = cubicw(tx - (float)(k - 1));
        wy[k] = cubicw(ty - (float)(k - 1));
        int a = x0 + (k - 1); ix[k] = min(max(a, 0), 17);
        a = y0 + (k - 1);     iy[k] = min(max(a, 0), 17);
    }
    float acc[3];
    #pragma unroll
    for (int c = 0; c < 3; c++) {
        const float* src = f0 + (b * 3 + c) * 324;
        float a = 0.f;
        #pragma unroll
        for (int ky = 0; ky < 4; ky++) {
            float rowv = 0.f;
            #pragma unroll
            for (int kx = 0; kx < 4; kx++) rowv += wx[kx] * src[iy[ky] * 18 + ix[kx]];
            a += wy[ky] * rowv;
        }
        acc[c] = a;
    }
    return make_float4(acc[0], acc[1], acc[2], 0.f);
}

// ---------------- linear + w2 B-frag prep + w1 f16 pack ----------------
__global__ void linear_prep_kernel(const float* __restrict__ x,
                                   const float* __restrict__ W,
                                   const float* __restrict__ bias,
                                   float* __restrict__ f0,
                                   const float* __restrict__ w2s,
                                   __half* __restrict__ wsB,
                                   const float* __restrict__ w1s,
                                   const float* __restrict__ b1s,
                                   __half* __restrict__ wsW1) {
    int blk = blockIdx.x;
    if (blk == 1945) {   // pack w1/b1 (4 stages x 32 ch) into f16 quads (w0,w1,w2,b)
        int tid = threadIdx.x;
        if (tid < 128) {
            int s = tid >> 5, c = tid & 31;
            wsW1[tid * 4 + 0] = __float2half(w1s[s * 96 + c * 3 + 0]);
            wsW1[tid * 4 + 1] = __float2half(w1s[s * 96 + c * 3 + 1]);
            wsW1[tid * 4 + 2] = __float2half(w1s[s * 96 + c * 3 + 2]);
            wsW1[tid * 4 + 3] = __float2half(b1s[s * 32 + c]);
        }
        return;
    }
    if (blk == 1944) {   // pack w2 (4 stages) into f16 MFMA fragments
        int tid = threadIdx.x;
        int s = tid >> 6, l = tid & 63;
        int n0 = l & 15, kq = l >> 4;
        const float* w2 = w2s + s * 1024;
        __half* dst = wsB + (size_t)tid * 16;
        #pragma unroll
        for (int j = 0; j < 8; j++) {
            dst[j]     = __float2half(w2[n0 * QC + kq * 8 + j]);
            dst[8 + j] = __float2half(w2[(n0 + 16) * QC + kq * 8 + j]);
        }
        return;
    }
    int gwave = (blk * blockDim.x + threadIdx.x) >> 6;
    int lane = threadIdx.x & 63;
    if (gwave >= BATCH * 972) return;
    int b = gwave / 972, j = gwave % 972;
    const float* xr = x + b * 1000;
    const float* wr = W + j * 1000;
    float s = 0.f;
    for (int k = lane; k < 1000; k += 64)
        s += xr[k] * wr[k];
    #pragma unroll
    for (int off = 32; off; off >>= 1) s += __shfl_down(s, off, 64);
    if (lane == 0) f0[gwave] = s + bias[j];
}

// ---------------- q precompute: per-stage whole-image range_proj (R8-validated) ----------------
// Reads guid planes directly (guid4 pack eliminated). Per-stage launch right before its
// jbu keeps the 25.7 MB qimg L3-resident (R9 lesson: batching 4 stages = HBM round-trip).
__global__ __launch_bounds__(256) void q_kernel(
    const float* __restrict__ guid,
    const __half* __restrict__ wsW1,
    const __half* __restrict__ wsB, const float* __restrict__ b2,
    float4* __restrict__ qimg,
    int stage)
{
    const int tid = threadIdx.x;
    const int l = tid & 63;
    const int gw = (blockIdx.x * 256 + tid) >> 6;    // 0..3135 (784 blocks x 4 waves)
    const int n0 = l & 15, kq = l >> 4;
    const int b = gw / 392;                          // 392 waves per batch image
    const int pix0 = (gw - b * 392) * 128;

    const v8h* Bp = (const v8h*)(wsB + ((size_t)stage * 64 + l) * 16);
    const v8h W2a = Bp[0], W2b = Bp[1];
    const float4 b2a = *(const float4*)(b2 + 4 * kq);
    const float4 b2b = *(const float4*)(b2 + 16 + 4 * kq);
    union { _Float16 h[32]; float4 f4[4]; } W1;
    {
        const float4* wp = (const float4*)(wsW1 + stage * 128 + kq * 32);
        W1.f4[0] = wp[0]; W1.f4[1] = wp[1]; W1.f4[2] = wp[2]; W1.f4[3] = wp[3];
    }
    const int plane0 = kq >> 1;
    const int boff   = (kq & 1) * 8;
    const float* gb = guid + (size_t)b * 3 * HW;
    char* qc = (char*)qimg;

    #pragma unroll 1
    for (int it = 0; it < 8; it++) {
        int pix = pix0 + it * 16 + n0;
        float gx = gb[pix];
        float gy = gb[HW + pix];
        float gz = gb[2 * HW + pix];
        union { _Float16 h[8]; v8h v; } A;
        #pragma unroll
        for (int j = 0; j < 8; j++) {
            float vv = fmaf((float)W1.h[j * 4], gx,
                       fmaf((float)W1.h[j * 4 + 1], gy,
                       fmaf((float)W1.h[j * 4 + 2], gz, (float)W1.h[j * 4 + 3])));
            A.h[j] = (_Float16)gelu_fast(vv);
        }
        v4f D0 = {0.f, 0.f, 0.f, 0.f}, D1 = {0.f, 0.f, 0.f, 0.f};
        D0 = __builtin_amdgcn_mfma_f32_16x16x32_f16(W2a, A.v, D0, 0, 0, 0);
        D1 = __builtin_amdgcn_mfma_f32_16x16x32_f16(W2b, A.v, D1, 0, 0, 0);
        union { _Float16 h[4]; uint2 u; } q0, q1;
        q0.h[0] = (_Float16)(D0[0] + b2a.x);
        q0.h[1] = (_Float16)(D0[1] + b2a.y);
        q0.h[2] = (_Float16)(D0[2] + b2a.z);
        q0.h[3] = (_Float16)(D0[3] + b2a.w);
        q1.h[0] = (_Float16)(D1[0] + b2b.x);
        q1.h[1] = (_Float16)(D1[1] + b2b.y);
        q1.h[2] = (_Float16)(D1[2] + b2b.z);
        q1.h[3] = (_Float16)(D1[3] + b2b.w);
        *(uint2*)(qc + ((size_t)(b * 4 + plane0) * HW + pix) * 16 + boff)     = q0.u;
        *(uint2*)(qc + ((size_t)(b * 4 + 2 + plane0) * HW + pix) * 16 + boff) = q1.u;
    }
}

// ---------------- fused JBU: stage q window -> MFMA scores -> exp2 -> MFMA conv ----------------
// R11: unroll 1 (R8-exact streaming, direct A/B winner vs unroll 2); stage 0 computes
// its hr tile in-kernel from f0 (bicubic_kernel dispatch + 6.4 MB round-trip removed;
// identical arithmetic -> bitwise-same output).
__global__ __launch_bounds__(256, 4) void jbu_kernel(
    const float4* __restrict__ qimg,
    const float4* __restrict__ hr4,
    const float* __restrict__ f0,
    float4* __restrict__ out4,
    float* __restrict__ outP,
    const float* __restrict__ temps,
    const float* __restrict__ sigmas,
    int stage)
{
    __shared__ __align__(16) char smem[SMEM_B];
    _Float16* hrh = (_Float16*)smem;            // [8][22][24] f16
    char* sqb = smem + HRH_B;                   // q tile f16 chunk-planar [4][CS] float4
    float4* sqf4 = (float4*)sqb;

    const int tx = threadIdx.x, ty = threadIdx.y;
    const int tid = ty * TILE + tx;
    const int b = blockIdx.z;
    const int h0 = blockIdx.y * TILE, w0 = blockIdx.x * TILE;

    // ---- stage q window (4 planes) + hr tile (f16 hi/lo) ----
    const float4* qb = qimg + (size_t)b * 4 * HW;
    const float4* hb = hr4 + (size_t)b * HW;
    for (int i = tid; i < TPIX; i += 256) {
        int r = i / TP, cx = i % TP;
        int gh = refl(h0 - RAD + r), gw = refl(w0 - RAD + cx);
        size_t gpix = (size_t)gh * GWW + gw;
        sqf4[i]          = qb[gpix];
        sqf4[CS + i]     = qb[HW + gpix];
        sqf4[2 * CS + i] = qb[2 * HW + gpix];
        sqf4[3 * CS + i] = qb[3 * HW + gpix];
        float4 v;
        if (stage == 0) v = bicubic_px(f0, b, gh, gw);   // uniform branch per launch
        else            v = hb[gpix];
        _Float16 hx = (_Float16)v.x, hy = (_Float16)v.y, hz = (_Float16)v.z;
        int base = r * HRH_COLS + cx;
        hrh[0 * PSTR + base] = hx;
        hrh[1 * PSTR + base] = hy;
        hrh[2 * PSTR + base] = hz;
        hrh[3 * PSTR + base] = (_Float16)1.0f;
        hrh[4 * PSTR + base] = (_Float16)(v.x - (float)hx);
        hrh[5 * PSTR + base] = (_Float16)(v.y - (float)hy);
        hrh[6 * PSTR + base] = (_Float16)(v.z - (float)hz);
        hrh[7 * PSTR + base] = (_Float16)0.0f;
    }
    // zero pad cols 22,23 (read by masked-0 weights; must be finite, not LDS residue)
    for (int i = tid; i < 8 * TP * 2; i += 256) {
        int p = i / (TP * 2), rem = i % (TP * 2);
        int r = rem >> 1, cc = 22 + (rem & 1);
        hrh[p * PSTR + r * HRH_COLS + cc] = (_Float16)0.0f;
    }
    __syncthreads();   // hrh + sq ready

    // ---- streaming: MFMA scores -> exp2 weights -> MFMA conv (R8-exact) ----
    const int wv = tid >> 6;
    const int l = tid & 63;
    const int g = l >> 4, c = l & 15;      // g = k-chunk group, c = center col

    float t = __expf(temps[stage]);
    t = fminf(fmaxf(t, 1e-4f), 1e4f);
    const float tl2 = t * L2E;             // folded: exp(t*s+lc) = exp2(s*tl2 + lc2)
    float sig = sigmas[stage];
    float inv2s2 = 1.f / (2.f * sig * sig);
    float sdv[DIAM];
    #pragma unroll
    for (int i = 0; i < DIAM; i++) {
        float d = (float)(i - 3) * (1.f / 3.f);
        sdv[i] = __expf(-d * d * inv2s2);
    }
    // lc2[jj]: log2-domain spatial-x for tap k = 8g+jj at center c; -1.44e38 masks
    float lc2[8];
    #pragma unroll
    for (int jj = 0; jj < 8; jj++) {
        int dj = 8 * g + jj - c;
        float d = (float)(dj - 3) * (1.f / 3.f);
        lc2[jj] = (dj >= 0 && dj <= 6) ? (-d * d * inv2s2 * L2E) : -1.44e38f;
    }
    // neighbor-col loads (per lane, m = c): sigma_cb(c) clamped to row end
    const int nbb = 8 * (c >> 2) + (c & 3);
    const int nb0 = min(nbb, 21);
    const int nb1 = min(nbb + 4, 21);
    const int pA = c & 3;                  // hr channel plane for conv A-frag

    #pragma unroll 1
    for (int rr = 0; rr < 4; rr++) {
        const int row = wv * 4 + rr;
        // center B-frag (reused across di/cb): q[center row][col c][chunk g]
        const v8h Bc = *(const v8h*)(sqb + (size_t)(g * CS + (row + RAD) * TP + RAD + c) * 16);
        v4f D2 = {0.f, 0.f, 0.f, 0.f};
        #pragma unroll
        for (int di = 0; di < DIAM; di++) {
            const int prow = row + di;
            const v8h A0 = *(const v8h*)(sqb + (size_t)(g * CS + prow * TP + nb0) * 16);
            const v8h A1 = *(const v8h*)(sqb + (size_t)(g * CS + prow * TP + nb1) * 16);
            v4f S0 = {0.f, 0.f, 0.f, 0.f}, S1 = {0.f, 0.f, 0.f, 0.f};
            S0 = __builtin_amdgcn_mfma_f32_16x16x32_f16(A0, Bc, S0, 0, 0, 0);
            S1 = __builtin_amdgcn_mfma_f32_16x16x32_f16(A1, Bc, S1, 0, 0, 0);
            const float sy = sdv[di];
            union { _Float16 h[8]; v8h v; } Wg;
            #pragma unroll
            for (int j = 0; j < 4; j++) {
                Wg.h[j]     = (_Float16)(__builtin_amdgcn_exp2f(fmaf(S0[j], tl2, lc2[j])) * sy);
                Wg.h[4 + j] = (_Float16)(__builtin_amdgcn_exp2f(fmaf(S1[j], tl2, lc2[4 + j])) * sy);
            }
            const v8h Hh = *(const v8h*)(smem + (size_t)((pA * TP + prow) * HRH_COLS + 8 * g) * 2);
            const v8h Hl = *(const v8h*)(smem + (size_t)(((pA + 4) * TP + prow) * HRH_COLS + 8 * g) * 2);
            D2 = __builtin_amdgcn_mfma_f32_16x16x32_f16(Hh, Wg.v, D2, 0, 0, 0);
            D2 = __builtin_amdgcn_mfma_f32_16x16x32_f16(Hl, Wg.v, D2, 0, 0, 0);
        }
        if (l < 16) {   // lanes 0..15 hold D2 rows 0..3 = {x,y,z,wsum} for center c
            float rk = 1.f / fmaxf(D2[3], 1e-7f);   // reference floor: clip(wsum, 1e-7)
            if (stage < 3) {
                out4[(size_t)b * HW + (size_t)(h0 + row) * GWW + (w0 + c)] =
                    make_float4(D2[0] * rk, D2[1] * rk, D2[2] * rk, 0.f);
            } else {
                size_t obase = (size_t)b * 3 * HW + (size_t)(h0 + row) * GWW + (w0 + c);
                outP[obase]          = D2[0] * rk;
                outP[obase + HW]     = D2[1] * rk;
                outP[obase + 2 * HW] = D2[2] * rk;
            }
        }
    }
}

extern "C" void kernel_launch(void* const* d_in, const int* in_sizes, int n_in,
                              void* d_out, int out_size, void* d_ws, size_t ws_size,
                              hipStream_t stream) {
    const float* x      = (const float*)d_in[0];
    const float* guid   = (const float*)d_in[1];
    const float* lw     = (const float*)d_in[2];
    const float* lb     = (const float*)d_in[3];
    const float* w1s    = (const float*)d_in[4];
    const float* b1s    = (const float*)d_in[5];
    const float* w2s    = (const float*)d_in[6];
    const float* b2s    = (const float*)d_in[7];
    const float* temps  = (const float*)d_in[8];
    const float* sigmas = (const float*)d_in[9];

    char* ws = (char*)d_ws;
    const size_t P4_BYTES = (size_t)BATCH * HW * sizeof(float4);      // 6,422,528
    float4* hr4A  = (float4*)(ws + P4_BYTES);
    float4* hr4B  = (float4*)(ws + 2 * P4_BYTES);
    float*  f0    = (float*)(ws + 3 * P4_BYTES);                      // 31,104 B
    __half* wsB   = (__half*)(ws + 3 * P4_BYTES + 31104);             //  8,192 B
    __half* wsW1  = (__half*)(ws + 3 * P4_BYTES + 31104 + 8192);      //  1,024 B
    float4* qimg  = (float4*)(ws + 3 * P4_BYTES + 40320);             // 25,690,112 B (per-stage reuse)

    linear_prep_kernel<<<1946, 256, 0, stream>>>(
        x, lw, lb, f0, w2s, wsB, w1s, b1s, wsW1);

    dim3 jgrid(14, 14, BATCH), jblock(16, 16);
    const float4* hins[4]  = { hr4A, hr4B, hr4A, hr4B };   // hins[0] unused (stage 0 computes hr from f0)
    float4*       fouts[4] = { hr4B, hr4A, hr4B, nullptr };
    for (int s = 0; s < 4; s++) {
        q_kernel<<<784, 256, 0, stream>>>(guid, wsW1, wsB, b2s + s * 32, qimg, s);
        jbu_kernel<<<jgrid, jblock, 0, stream>>>(
            qimg, hins[s], f0, fouts[s], (s == 3) ? (float*)d_out : nullptr,
            temps, sigmas, s);
    }
}

// Round 12
// 277.959 us; speedup vs baseline: 1.1072x; 1.0226x over previous
//
#include <hip/hip_runtime.h>
#include <hip/hip_fp16.h>
#include <math.h>

#define GHH 224
#define GWW 224
#define HW (GHH*GWW)     // 50176
#define BATCH 8
#define RAD 3
#define DIAM 7
#define QC 32
#define TILE 16
#define TP (TILE + 2*RAD)   // 22
#define TPIX (TP*TP)        // 484
#define CS 485              // chunk-plane stride in float4 (proven layout)

// LDS layout: [hrh: 8 planes x 22 rows x 24 cols f16 = 8448 B][sq: 4*485*16 = 31040 B]
// hrh planes 0-3 = hi{x,y,z,1}, 4-7 = lo{x,y,z,0}. Total 39488 B -> 4 blocks/CU.
#define HRH_COLS 24
#define PSTR (TP*HRH_COLS)   // 528 halves per plane
#define HRH_B (8*PSTR*2)     // 8448 B
#define SMEM_B (HRH_B + 4*CS*16)  // 39488

#define L2E 1.44269504f

typedef _Float16 h2 __attribute__((ext_vector_type(2)));
typedef _Float16 v8h __attribute__((ext_vector_type(8)));
typedef float v4f __attribute__((ext_vector_type(4)));

__device__ __forceinline__ int refl(int i) {
    if (i < 0) i = -i;
    if (i >= GHH) i = 2 * GHH - 2 - i;
    return i;
}

__device__ __forceinline__ float gelu_fast(float v) {
    float u = 0.7978845608f * v * (1.f + 0.044715f * v * v);
    float e = __builtin_amdgcn_exp2f(u * (2.f * L2E));   // exp(2u), folded log2e
    float th = 1.f - 2.f / (e + 1.f);
    return 0.5f * v * (1.f + th);
}

__device__ __forceinline__ float cubicw(float d) {
    d = fabsf(d);
    if (d <= 1.f) return ((1.25f * d - 2.25f) * d) * d + 1.f;
    if (d < 2.f)  return ((-0.75f * d + 3.75f) * d - 6.f) * d + 3.f;
    return 0.f;
}

// packed f32->f16 pair convert (cvt_pkrtz when available)
__device__ __forceinline__ h2 cvt2_h2(float a, float b) {
#if defined(__has_builtin)
#if __has_builtin(__builtin_amdgcn_cvt_pkrtz) && __has_builtin(__builtin_bit_cast)
    return __builtin_bit_cast(h2, __builtin_amdgcn_cvt_pkrtz(a, b));
#else
    h2 r; r[0] = (_Float16)a; r[1] = (_Float16)b; return r;
#endif
#else
    h2 r; r[0] = (_Float16)a; r[1] = (_Float16)b; return r;
#endif
}

// Exact replica of the validated bicubic_kernel math for one output pixel.
__device__ __forceinline__ float4 bicubic_px(const float* __restrict__ f0, int b, int h, int w) {
    float xx = (w + 0.5f) * (18.f / 224.f) - 0.5f;
    float yy = (h + 0.5f) * (18.f / 224.f) - 0.5f;
    float fx0 = floorf(xx), fy0 = floorf(yy);
    int x0 = (int)fx0, y0 = (int)fy0;
    float tx = xx - fx0, ty = yy - fy0;
    float wx[4], wy[4];
    int ix[4], iy[4];
    #pragma unroll
    for (int k = 0; k < 4; k++) {
        wx[k] = cubicw(tx - (float)(k - 1));
        wy[k] = cubicw(ty - (float)(k - 1));
        int a = x0 + (k - 1); ix[k] = min(max(a, 0), 17);
        a = y0 + (k - 1);     iy[k] = min(max(a, 0), 17);
    }
    float acc[3];
    #pragma unroll
    for (int c = 0; c < 3; c++) {
        const float* src = f0 + (b * 3 + c) * 324;
        float a = 0.f;
        #pragma unroll
        for (int ky = 0; ky < 4; ky++) {
            float rowv = 0.f;
            #pragma unroll
            for (int kx = 0; kx < 4; kx++) rowv += wx[kx] * src[iy[ky] * 18 + ix[kx]];
            a += wy[ky] * rowv;
        }
        acc[c] = a;
    }
    return make_float4(acc[0], acc[1], acc[2], 0.f);
}

// ---------------- linear + w2 B-frag prep + w1 f16 pack ----------------
__global__ void linear_prep_kernel(const float* __restrict__ x,
                                   const float* __restrict__ W,
                                   const float* __restrict__ bias,
                                   float* __restrict__ f0,
                                   const float* __restrict__ w2s,
                                   __half* __restrict__ wsB,
                                   const float* __restrict__ w1s,
                                   const float* __restrict__ b1s,
                                   __half* __restrict__ wsW1) {
    int blk = blockIdx.x;
    if (blk == 1945) {   // pack w1/b1 (4 stages x 32 ch) into f16 quads (w0,w1,w2,b)
        int tid = threadIdx.x;
        if (tid < 128) {
            int s = tid >> 5, c = tid & 31;
            wsW1[tid * 4 + 0] = __float2half(w1s[s * 96 + c * 3 + 0]);
            wsW1[tid * 4 + 1] = __float2half(w1s[s * 96 + c * 3 + 1]);
            wsW1[tid * 4 + 2] = __float2half(w1s[s * 96 + c * 3 + 2]);
            wsW1[tid * 4 + 3] = __float2half(b1s[s * 32 + c]);
        }
        return;
    }
    if (blk == 1944) {   // pack w2 (4 stages) into f16 MFMA fragments
        int tid = threadIdx.x;
        int s = tid >> 6, l = tid & 63;
        int n0 = l & 15, kq = l >> 4;
        const float* w2 = w2s + s * 1024;
        __half* dst = wsB + (size_t)tid * 16;
        #pragma unroll
        for (int j = 0; j < 8; j++) {
            dst[j]     = __float2half(w2[n0 * QC + kq * 8 + j]);
            dst[8 + j] = __float2half(w2[(n0 + 16) * QC + kq * 8 + j]);
        }
        return;
    }
    int gwave = (blk * blockDim.x + threadIdx.x) >> 6;
    int lane = threadIdx.x & 63;
    if (gwave >= BATCH * 972) return;
    int b = gwave / 972, j = gwave % 972;
    const float* xr = x + b * 1000;
    const float* wr = W + j * 1000;
    float s = 0.f;
    for (int k = lane; k < 1000; k += 64)
        s += xr[k] * wr[k];
    #pragma unroll
    for (int off = 32; off; off >>= 1) s += __shfl_down(s, off, 64);
    if (lane == 0) f0[gwave] = s + bias[j];
}

// ---------------- q precompute: per-stage whole-image range_proj ----------------
// R12: q scaled by sqrt(t) so the score MFMA in jbu yields z = t*s directly
// (deletes per-slot t-multiply before the weight poly). Per-stage launch keeps the
// 25.7 MB qimg L3-resident (R9 lesson).
__global__ __launch_bounds__(256) void q_kernel(
    const float* __restrict__ guid,
    const __half* __restrict__ wsW1,
    const __half* __restrict__ wsB, const float* __restrict__ b2,
    const float* __restrict__ temps,
    float4* __restrict__ qimg,
    int stage)
{
    const int tid = threadIdx.x;
    const int l = tid & 63;
    const int gw = (blockIdx.x * 256 + tid) >> 6;    // 0..3135 (784 blocks x 4 waves)
    const int n0 = l & 15, kq = l >> 4;
    const int b = gw / 392;                          // 392 waves per batch image
    const int pix0 = (gw - b * 392) * 128;

    float t = __expf(temps[stage]);
    t = fminf(fmaxf(t, 1e-4f), 1e4f);
    const float rt = sqrtf(t);

    const v8h* Bp = (const v8h*)(wsB + ((size_t)stage * 64 + l) * 16);
    const v8h W2a = Bp[0], W2b = Bp[1];
    const float4 b2a = *(const float4*)(b2 + 4 * kq);
    const float4 b2b = *(const float4*)(b2 + 16 + 4 * kq);
    union { _Float16 h[32]; float4 f4[4]; } W1;
    {
        const float4* wp = (const float4*)(wsW1 + stage * 128 + kq * 32);
        W1.f4[0] = wp[0]; W1.f4[1] = wp[1]; W1.f4[2] = wp[2]; W1.f4[3] = wp[3];
    }
    const int plane0 = kq >> 1;
    const int boff   = (kq & 1) * 8;
    const float* gb = guid + (size_t)b * 3 * HW;
    char* qc = (char*)qimg;

    #pragma unroll 1
    for (int it = 0; it < 8; it++) {
        int pix = pix0 + it * 16 + n0;
        float gx = gb[pix];
        float gy = gb[HW + pix];
        float gz = gb[2 * HW + pix];
        union { _Float16 h[8]; v8h v; } A;
        #pragma unroll
        for (int j = 0; j < 8; j++) {
            float vv = fmaf((float)W1.h[j * 4], gx,
                       fmaf((float)W1.h[j * 4 + 1], gy,
                       fmaf((float)W1.h[j * 4 + 2], gz, (float)W1.h[j * 4 + 3])));
            A.h[j] = (_Float16)gelu_fast(vv);
        }
        v4f D0 = {0.f, 0.f, 0.f, 0.f}, D1 = {0.f, 0.f, 0.f, 0.f};
        D0 = __builtin_amdgcn_mfma_f32_16x16x32_f16(W2a, A.v, D0, 0, 0, 0);
        D1 = __builtin_amdgcn_mfma_f32_16x16x32_f16(W2b, A.v, D1, 0, 0, 0);
        union { _Float16 h[4]; uint2 u; } q0, q1;
        q0.h[0] = (_Float16)((D0[0] + b2a.x) * rt);
        q0.h[1] = (_Float16)((D0[1] + b2a.y) * rt);
        q0.h[2] = (_Float16)((D0[2] + b2a.z) * rt);
        q0.h[3] = (_Float16)((D0[3] + b2a.w) * rt);
        q1.h[0] = (_Float16)((D1[0] + b2b.x) * rt);
        q1.h[1] = (_Float16)((D1[1] + b2b.y) * rt);
        q1.h[2] = (_Float16)((D1[2] + b2b.z) * rt);
        q1.h[3] = (_Float16)((D1[3] + b2b.w) * rt);
        *(uint2*)(qc + ((size_t)(b * 4 + plane0) * HW + pix) * 16 + boff)     = q0.u;
        *(uint2*)(qc + ((size_t)(b * 4 + 2 + plane0) * HW + pix) * 16 + boff) = q1.u;
    }
}

// ---------------- fused JBU: stage q window -> MFMA scores -> pk-f16 Taylor weights -> MFMA conv ----------------
// R12: weight epilogue exp2(f32, quarter-rate) replaced by exp(z) ~ Taylor-4 in packed
// f16 (z = t*s from the sqrt(t)-scaled q). Mask + spatial-x fold into exact f16
// constants SX[jj] (0 on invalid band -> exact zero weights, no -inf handling).
__global__ __launch_bounds__(256, 4) void jbu_kernel(
    const float4* __restrict__ qimg,
    const float4* __restrict__ hr4,
    const float* __restrict__ f0,
    float4* __restrict__ out4,
    float* __restrict__ outP,
    const float* __restrict__ temps,
    const float* __restrict__ sigmas,
    int stage)
{
    __shared__ __align__(16) char smem[SMEM_B];
    _Float16* hrh = (_Float16*)smem;            // [8][22][24] f16
    char* sqb = smem + HRH_B;                   // q tile f16 chunk-planar [4][CS] float4
    float4* sqf4 = (float4*)sqb;

    const int tx = threadIdx.x, ty = threadIdx.y;
    const int tid = ty * TILE + tx;
    const int b = blockIdx.z;
    const int h0 = blockIdx.y * TILE, w0 = blockIdx.x * TILE;

    // ---- stage q window (4 planes) + hr tile (f16 hi/lo) ----
    const float4* qb = qimg + (size_t)b * 4 * HW;
    const float4* hb = hr4 + (size_t)b * HW;
    for (int i = tid; i < TPIX; i += 256) {
        int r = i / TP, cx = i % TP;
        int gh = refl(h0 - RAD + r), gw = refl(w0 - RAD + cx);
        size_t gpix = (size_t)gh * GWW + gw;
        sqf4[i]          = qb[gpix];
        sqf4[CS + i]     = qb[HW + gpix];
        sqf4[2 * CS + i] = qb[2 * HW + gpix];
        sqf4[3 * CS + i] = qb[3 * HW + gpix];
        float4 v;
        if (stage == 0) v = bicubic_px(f0, b, gh, gw);   // uniform branch per launch
        else            v = hb[gpix];
        _Float16 hx = (_Float16)v.x, hy = (_Float16)v.y, hz = (_Float16)v.z;
        int base = r * HRH_COLS + cx;
        hrh[0 * PSTR + base] = hx;
        hrh[1 * PSTR + base] = hy;
        hrh[2 * PSTR + base] = hz;
        hrh[3 * PSTR + base] = (_Float16)1.0f;
        hrh[4 * PSTR + base] = (_Float16)(v.x - (float)hx);
        hrh[5 * PSTR + base] = (_Float16)(v.y - (float)hy);
        hrh[6 * PSTR + base] = (_Float16)(v.z - (float)hz);
        hrh[7 * PSTR + base] = (_Float16)0.0f;
    }
    // zero pad cols 22,23 (read by zero-weight slots; must be finite, not LDS residue)
    for (int i = tid; i < 8 * TP * 2; i += 256) {
        int p = i / (TP * 2), rem = i % (TP * 2);
        int r = rem >> 1, cc = 22 + (rem & 1);
        hrh[p * PSTR + r * HRH_COLS + cc] = (_Float16)0.0f;
    }
    __syncthreads();   // hrh + sq ready

    // ---- streaming: MFMA scores -> Taylor-4 pk-f16 weights -> MFMA conv ----
    const int wv = tid >> 6;
    const int l = tid & 63;
    const int g = l >> 4, c = l & 15;      // g = k-chunk group, c = center col

    float sig = sigmas[stage];
    float inv2s2 = 1.f / (2.f * sig * sig);
    float sdv[DIAM];
    #pragma unroll
    for (int i = 0; i < DIAM; i++) {
        float d = (float)(i - 3) * (1.f / 3.f);
        sdv[i] = __expf(-d * d * inv2s2);
    }
    // SX[jj]: spatial-x weight (exact) for tap k = 8g+jj at center c; 0 masks dj outside [0,6]
    float sv[8];
    #pragma unroll
    for (int jj = 0; jj < 8; jj++) {
        int dj = 8 * g + jj - c;
        float d = (float)(dj - 3) * (1.f / 3.f);
        sv[jj] = (dj >= 0 && dj <= 6) ? __expf(-d * d * inv2s2) : 0.f;
    }
    const h2 SX0 = {(_Float16)sv[0], (_Float16)sv[1]};
    const h2 SX1 = {(_Float16)sv[2], (_Float16)sv[3]};
    const h2 SX2 = {(_Float16)sv[4], (_Float16)sv[5]};
    const h2 SX3 = {(_Float16)sv[6], (_Float16)sv[7]};
    // Taylor-4 coefficients for exp(z), packed f16 (T4 > 0 for all z)
    const h2 C4 = {(_Float16)0.041666668f, (_Float16)0.041666668f};
    const h2 C3 = {(_Float16)0.16666667f, (_Float16)0.16666667f};
    const h2 C2 = {(_Float16)0.5f, (_Float16)0.5f};
    const h2 C1 = {(_Float16)1.0f, (_Float16)1.0f};
    const h2 C0 = {(_Float16)1.0f, (_Float16)1.0f};

    // neighbor-col loads (per lane, m = c): sigma_cb(c) clamped to row end
    const int nbb = 8 * (c >> 2) + (c & 3);
    const int nb0 = min(nbb, 21);
    const int nb1 = min(nbb + 4, 21);
    const int pA = c & 3;                  // hr channel plane for conv A-frag

    #pragma unroll 1
    for (int rr = 0; rr < 4; rr++) {
        const int row = wv * 4 + rr;
        // center B-frag (reused across di/cb): q[center row][col c][chunk g]
        const v8h Bc = *(const v8h*)(sqb + (size_t)(g * CS + (row + RAD) * TP + RAD + c) * 16);
        v4f D2 = {0.f, 0.f, 0.f, 0.f};
        #pragma unroll
        for (int di = 0; di < DIAM; di++) {
            const int prow = row + di;
            const v8h A0 = *(const v8h*)(sqb + (size_t)(g * CS + prow * TP + nb0) * 16);
            const v8h A1 = *(const v8h*)(sqb + (size_t)(g * CS + prow * TP + nb1) * 16);
            v4f S0 = {0.f, 0.f, 0.f, 0.f}, S1 = {0.f, 0.f, 0.f, 0.f};
            S0 = __builtin_amdgcn_mfma_f32_16x16x32_f16(A0, Bc, S0, 0, 0, 0);
            S1 = __builtin_amdgcn_mfma_f32_16x16x32_f16(A1, Bc, S1, 0, 0, 0);
            const h2 syp = {(_Float16)sdv[di], (_Float16)sdv[di]};
            union { h2 p[4]; v8h v; } Wg;
            {   // pair 0: slots jj=0,1 from S0[0..1]
                h2 z = cvt2_h2(S0[0], S0[1]);
                h2 e = z * C4 + C3; e = e * z + C2; e = e * z + C1; e = e * z + C0;
                Wg.p[0] = e * SX0 * syp;
            }
            {   // pair 1: slots jj=2,3 from S0[2..3]
                h2 z = cvt2_h2(S0[2], S0[3]);
                h2 e = z * C4 + C3; e = e * z + C2; e = e * z + C1; e = e * z + C0;
                Wg.p[1] = e * SX1 * syp;
            }
            {   // pair 2: slots jj=4,5 from S1[0..1]
                h2 z = cvt2_h2(S1[0], S1[1]);
                h2 e = z * C4 + C3; e = e * z + C2; e = e * z + C1; e = e * z + C0;
                Wg.p[2] = e * SX2 * syp;
            }
            {   // pair 3: slots jj=6,7 from S1[2..3]
                h2 z = cvt2_h2(S1[2], S1[3]);
                h2 e = z * C4 + C3; e = e * z + C2; e = e * z + C1; e = e * z + C0;
                Wg.p[3] = e * SX3 * syp;
            }
            const v8h Hh = *(const v8h*)(smem + (size_t)((pA * TP + prow) * HRH_COLS + 8 * g) * 2);
            const v8h Hl = *(const v8h*)(smem + (size_t)(((pA + 4) * TP + prow) * HRH_COLS + 8 * g) * 2);
            D2 = __builtin_amdgcn_mfma_f32_16x16x32_f16(Hh, Wg.v, D2, 0, 0, 0);
            D2 = __builtin_amdgcn_mfma_f32_16x16x32_f16(Hl, Wg.v, D2, 0, 0, 0);
        }
        if (l < 16) {   // lanes 0..15 hold D2 rows 0..3 = {x,y,z,wsum} for center c
            float rk = 1.f / fmaxf(D2[3], 1e-7f);   // reference floor: clip(wsum, 1e-7)
            if (stage < 3) {
                out4[(size_t)b * HW + (size_t)(h0 + row) * GWW + (w0 + c)] =
                    make_float4(D2[0] * rk, D2[1] * rk, D2[2] * rk, 0.f);
            } else {
                size_t obase = (size_t)b * 3 * HW + (size_t)(h0 + row) * GWW + (w0 + c);
                outP[obase]          = D2[0] * rk;
                outP[obase + HW]     = D2[1] * rk;
                outP[obase + 2 * HW] = D2[2] * rk;
            }
        }
    }
    (void)temps;
}

extern "C" void kernel_launch(void* const* d_in, const int* in_sizes, int n_in,
                              void* d_out, int out_size, void* d_ws, size_t ws_size,
                              hipStream_t stream) {
    const float* x      = (const float*)d_in[0];
    const float* guid   = (const float*)d_in[1];
    const float* lw     = (const float*)d_in[2];
    const float* lb     = (const float*)d_in[3];
    const float* w1s    = (const float*)d_in[4];
    const float* b1s    = (const float*)d_in[5];
    const float* w2s    = (const float*)d_in[6];
    const float* b2s    = (const float*)d_in[7];
    const float* temps  = (const float*)d_in[8];
    const float* sigmas = (const float*)d_in[9];

    char* ws = (char*)d_ws;
    const size_t P4_BYTES = (size_t)BATCH * HW * sizeof(float4);      // 6,422,528
    float4* hr4A  = (float4*)(ws + P4_BYTES);
    float4* hr4B  = (float4*)(ws + 2 * P4_BYTES);
    float*  f0    = (float*)(ws + 3 * P4_BYTES);                      // 31,104 B
    __half* wsB   = (__half*)(ws + 3 * P4_BYTES + 31104);             //  8,192 B
    __half* wsW1  = (__half*)(ws + 3 * P4_BYTES + 31104 + 8192);      //  1,024 B
    float4* qimg  = (float4*)(ws + 3 * P4_BYTES + 40320);             // 25,690,112 B (per-stage reuse)

    linear_prep_kernel<<<1946, 256, 0, stream>>>(
        x, lw, lb, f0, w2s, wsB, w1s, b1s, wsW1);

    dim3 jgrid(14, 14, BATCH), jblock(16, 16);
    const float4* hins[4]  = { hr4A, hr4B, hr4A, hr4B };   // hins[0] unused (stage 0 computes hr from f0)
    float4*       fouts[4] = { hr4B, hr4A, hr4B, nullptr };
    for (int s = 0; s < 4; s++) {
        q_kernel<<<784, 256, 0, stream>>>(guid, wsW1, wsB, b2s + s * 32, temps, qimg, s);
        jbu_kernel<<<jgrid, jblock, 0, stream>>>(
            qimg, hins[s], f0, fouts[s], (s == 3) ? (float*)d_out : nullptr,
            temps, sigmas, s);
    }
}